// Round 5
// baseline (89.439 us; speedup 1.0000x reference)
//
#include <hip/hip_runtime.h>
#include <hip/hip_bf16.h>
#include <math.h>

#define B_SZ   256
#define T_SZ   50
#define N_OBS  8192
#define N_KC   50

// d_ws is re-poisoned to 0xAA bytes before EVERY launch (harness contract),
// so the arrival counter deterministically starts at 0xAAAAAAAA.
#define POISON_U32 0xAAAAAAAAu

using f32x4 = __attribute__((ext_vector_type(4))) float;

// ---------------------------------------------------------------------------
// Single fused kernel: 256 blocks x 512 threads (1 block/CU, co-resident).
//   Phase 1: each block computes 1/256 of assign[] from one-hot A (400
//            coalesced float4 reads -> scattered dword stores), plus
//            sigmoid(kc_logits) into LDS.
//   Barrier: device-wide arrival counter in d_ws (starts at POISON_U32),
//            agent-scope release add + acquire spin.
//   Phase 2: wave 0 runs the 50-step serial BKT recurrence with per-KC state
//            in registers (lane k < 50) over wave-uniform __shfl broadcasts;
//            meanwhile waves issue their int4 assign prefetches.
//   Phase 3: all 8 waves expand the 8192-element state row via LDS gather +
//            nontemporal float4 stores.
// ---------------------------------------------------------------------------
__global__ void __launch_bounds__(512) k_fused(
        const int*   __restrict__ prev_kc,
        const int*   __restrict__ curr_kc,
        const float* __restrict__ prev_corr,
        const float* __restrict__ kc_logits,
        const float* __restrict__ A,
        int*          assign,          // d_ws, 32 KB
        unsigned int* counter,         // d_ws + 32 KB
        float* __restrict__ probs_out, // [B][T]
        float* __restrict__ state_out) // [B][N_OBS]
{
    const int b    = blockIdx.x;
    const int tid  = threadIdx.x;   // 0..511
    const int lane = tid & 63;
    const int wave = tid >> 6;

    __shared__ float s_probs[N_KC * 5 + 6];
    __shared__ float s_state[64];

    // ---- Phase 1: this block's share of assign (102400 float4 / 256 = 400).
    if (tid < 400) {
        const int idx = b * 400 + tid;          // float4 index into A
        const float4 v = ((const float4*)A)[idx];
        const int e = idx * 4;
        if (v.x > 0.5f) assign[(e + 0) / N_KC] = (e + 0) % N_KC;
        if (v.y > 0.5f) assign[(e + 1) / N_KC] = (e + 1) % N_KC;
        if (v.z > 0.5f) assign[(e + 2) / N_KC] = (e + 2) % N_KC;
        if (v.w > 0.5f) assign[(e + 3) / N_KC] = (e + 3) % N_KC;
    }

    // Independent of assign: sigmoid table into LDS.
    for (int i = tid; i < N_KC * 5; i += 512) {
        float x = kc_logits[i];
        s_probs[i] = 1.0f / (1.0f + expf(-x));
    }

    // ---- Device-wide arrival barrier.
    __syncthreads();                 // block's assign stores issued & waited
    if (tid == 0) {
        __threadfence();             // agent-scope: flush block's writes
        __hip_atomic_fetch_add(counter, 1u, __ATOMIC_ACQ_REL,
                               __HIP_MEMORY_SCOPE_AGENT);
        while (__hip_atomic_load(counter, __ATOMIC_ACQUIRE,
                                 __HIP_MEMORY_SCOPE_AGENT)
               != POISON_U32 + (unsigned)B_SZ) {
            __builtin_amdgcn_s_sleep(1);
        }
    }
    __syncthreads();                 // whole block sees completed assign[]

    // ---- Phase 2/3 prefetch: each thread's 4 int4 of assign (independent
    // of the scan; loads complete behind wave 0's serial recurrence).
    const int4* a4p = (const int4*)assign;
    int4 pa[4];
    #pragma unroll
    for (int k = 0; k < 4; ++k) pa[k] = a4p[tid + k * 512];

    if (wave == 0) {
        // Per-step constants: lane t (t < T) holds the values for timestep t.
        int   ka = 0, kc = 0;
        float po0 = 0.f, po1 = 0.f, pl = 0.f, pf = 0.f, cp2 = 0.f, cp3 = 0.f;
        if (lane < T_SZ) {
            int   pk   = prev_kc[b * T_SZ + lane];
            int   ck   = curr_kc[b * T_SZ + lane];
            float corr = prev_corr[b * T_SZ + lane];
            ka = assign[pk];
            kc = assign[ck];
            float pp0 = s_probs[ka * 5 + 0];
            float pp1 = s_probs[ka * 5 + 1];
            float pp2 = s_probs[ka * 5 + 2];
            float pp3 = s_probs[ka * 5 + 3];
            // prev_corr is exactly 0.0 or 1.0 -> pow() reduces to a select.
            bool c = corr > 0.5f;
            po0 = c ? pp2 : 1.0f - pp2;
            po1 = c ? pp3 : 1.0f - pp3;
            pl  = pp0;
            pf  = pp1;
            cp2 = s_probs[kc * 5 + 2];
            cp3 = s_probs[kc * 5 + 3];
        }

        // Initial per-KC state: lane k holds sigmoid(kc_logits[k,4]).
        float st = (lane < N_KC) ? s_probs[lane * 5 + 4] : 0.0f;

        float pc_mine = 0.0f;

        // t = 0: prediction only, no state update.
        {
            int   kc0 = __shfl(kc, 0);
            float cs  = __shfl(st, kc0);
            float c2  = __shfl(cp2, 0);
            float c3  = __shfl(cp3, 0);
            float pc  = c2 * (1.0f - cs) + c3 * cs;
            if (lane == 0) pc_mine = pc;
        }

        // t = 1..T-1: serial recurrence; all broadcasts are wave-uniform.
        for (int t = 1; t < T_SZ; ++t) {
            int   ka_t  = __shfl(ka, t);
            float po0_t = __shfl(po0, t);
            float po1_t = __shfl(po1, t);
            float pl_t  = __shfl(pl, t);
            float pf_t  = __shfl(pf, t);

            float ss    = __shfl(st, ka_t);
            float denom = po0_t * (1.0f - ss) + po1_t * ss;
            float filt  = po1_t * ss / denom;
            float pred  = pl_t * (1.0f - filt) + (1.0f - pf_t) * filt;
            if (lane == ka_t) st = pred;

            int   kc_t = __shfl(kc, t);
            float cs   = __shfl(st, kc_t);
            float c2   = __shfl(cp2, t);
            float c3   = __shfl(cp3, t);
            float pc   = c2 * (1.0f - cs) + c3 * cs;
            if (lane == t) pc_mine = pc;
        }

        if (lane < T_SZ) probs_out[b * T_SZ + lane] = pc_mine;
        s_state[lane] = st;
    }
    __syncthreads();

    // ---- Phase 3: expand. state_out[b][j] = s_state[assign[j]].
    f32x4* outp = (f32x4*)(state_out + (long)b * N_OBS);
    #pragma unroll
    for (int k = 0; k < 4; ++k) {
        const int i = tid + k * 512;
        const int4 a = pa[k];
        f32x4 v;
        v.x = s_state[a.x];
        v.y = s_state[a.y];
        v.z = s_state[a.z];
        v.w = s_state[a.w];
        __builtin_nontemporal_store(v, &outp[i]);
    }
}

extern "C" void kernel_launch(void* const* d_in, const int* in_sizes, int n_in,
                              void* d_out, int out_size, void* d_ws, size_t ws_size,
                              hipStream_t stream) {
    const int*   prev_kc   = (const int*)  d_in[0];
    const int*   curr_kc   = (const int*)  d_in[1];
    const float* prev_corr = (const float*)d_in[2];
    const float* kc_logits = (const float*)d_in[3];
    const float* A         = (const float*)d_in[4];

    float* probs_out = (float*)d_out;                 // B*T
    float* state_out = (float*)d_out + B_SZ * T_SZ;   // B*N_OBS

    int*          assign  = (int*)d_ws;                            // 32 KB
    unsigned int* counter = (unsigned int*)((char*)d_ws + 32768);  // 4 B

    k_fused<<<B_SZ, 512, 0, stream>>>(prev_kc, curr_kc, prev_corr,
                                      kc_logits, A,
                                      assign, counter,
                                      probs_out, state_out);
}

// Round 6
// 74.962 us; speedup vs baseline: 1.1931x; 1.1931x over previous
//
#include <hip/hip_runtime.h>
#include <hip/hip_bf16.h>
#include <math.h>

#define B_SZ   256
#define T_SZ   50
#define N_OBS  8192
#define N_KC   50

using f32x4 = __attribute__((ext_vector_type(4))) float;

// ---------------------------------------------------------------------------
// K1: assign[i] = column of the single 1.0 in one-hot row A[i,:].
//     A is scanned FLAT with float4 (fully coalesced, 1.6 MB); each one-hot
//     hit produces one scattered dword store (8192 total).
// ---------------------------------------------------------------------------
__global__ void __launch_bounds__(256) k_assign(
        const float* __restrict__ A,
        int* __restrict__ assign) {
    const int idx = blockIdx.x * 256 + threadIdx.x;   // float4 index
    // N_OBS*N_KC = 409600 floats = 102400 float4 -> exactly 400 blocks.
    const float4 v = ((const float4*)A)[idx];
    const int e = idx * 4;
    if (v.x > 0.5f) assign[(e + 0) / N_KC] = (e + 0) % N_KC;
    if (v.y > 0.5f) assign[(e + 1) / N_KC] = (e + 1) % N_KC;
    if (v.z > 0.5f) assign[(e + 2) / N_KC] = (e + 2) % N_KC;
    if (v.w > 0.5f) assign[(e + 3) / N_KC] = (e + 3) % N_KC;
}

// ---------------------------------------------------------------------------
// K2: one 512-thread block per batch element, fused scan + expand.
//     - all 8 waves: sigmoid(kc_logits) -> LDS; prefetch 4 int4 of assign
//       (loads complete behind wave 0's serial scan)
//     - wave 0: per-KC state in registers (lane k < 50), serial recurrence
//       over wave-uniform __shfl broadcasts; v_rcp_f32 instead of full
//       divide on the critical path (threshold 1.1e-2 >> rcp error)
//     - all 8 waves: expand 8192-element row via LDS gather + nontemporal
//       float4 stores (4 per thread, coalesced)
// ---------------------------------------------------------------------------
__global__ void __launch_bounds__(512) k_scan_expand(
        const int*   __restrict__ prev_kc,
        const int*   __restrict__ curr_kc,
        const float* __restrict__ prev_corr,
        const int*   __restrict__ assign,
        const float* __restrict__ kc_logits,
        float* __restrict__ probs_out,    // [B][T]
        float* __restrict__ state_out) {  // [B][N_OBS]
    const int b    = blockIdx.x;
    const int tid  = threadIdx.x;        // 0..511
    const int lane = tid & 63;
    const int wave = tid >> 6;

    __shared__ float s_probs[N_KC * 5 + 6];
    __shared__ float s_state[64];

    for (int i = tid; i < N_KC * 5; i += 512) {
        float x = kc_logits[i];
        s_probs[i] = __builtin_amdgcn_rcpf(1.0f + __expf(-x));
    }

    // Prefetch this thread's expand inputs NOW: the 4 int4 loads are
    // independent of the scan and complete while wave 0 runs it.
    const int4* a4p = (const int4*)assign;
    int4 pa[4];
    #pragma unroll
    for (int k = 0; k < 4; ++k) pa[k] = a4p[tid + k * 512];

    __syncthreads();

    if (wave == 0) {
        // Per-step constants: lane t (t < T) holds the values for timestep t.
        int   ka = 0, kc = 0;
        float po0 = 0.f, po1 = 0.f, pl = 0.f, pf = 0.f, cp2 = 0.f, cp3 = 0.f;
        if (lane < T_SZ) {
            int   pk   = prev_kc[b * T_SZ + lane];
            int   ck   = curr_kc[b * T_SZ + lane];
            float corr = prev_corr[b * T_SZ + lane];
            ka = assign[pk];
            kc = assign[ck];
            float pp0 = s_probs[ka * 5 + 0];
            float pp1 = s_probs[ka * 5 + 1];
            float pp2 = s_probs[ka * 5 + 2];
            float pp3 = s_probs[ka * 5 + 3];
            // prev_corr is exactly 0.0 or 1.0 -> pow() reduces to a select.
            bool c = corr > 0.5f;
            po0 = c ? pp2 : 1.0f - pp2;
            po1 = c ? pp3 : 1.0f - pp3;
            pl  = pp0;
            pf  = pp1;
            cp2 = s_probs[kc * 5 + 2];
            cp3 = s_probs[kc * 5 + 3];
        }

        // Initial per-KC state: lane k holds sigmoid(kc_logits[k,4]).
        float st = (lane < N_KC) ? s_probs[lane * 5 + 4] : 0.0f;

        float pc_mine = 0.0f;

        // t = 0: prediction only, no state update.
        {
            int   kc0 = __shfl(kc, 0);
            float cs  = __shfl(st, kc0);
            float c2  = __shfl(cp2, 0);
            float c3  = __shfl(cp3, 0);
            float pc  = c2 * (1.0f - cs) + c3 * cs;
            if (lane == 0) pc_mine = pc;
        }

        // t = 1..T-1: serial recurrence; all broadcasts are wave-uniform.
        // v_rcp_f32 (~1e-7 rel err) replaces the IEEE divide: the dependent
        // chain is 50 x (shfl, fma*3, rcp, shfl) -- this is the only serial
        // part of the whole problem.
        for (int t = 1; t < T_SZ; ++t) {
            int   ka_t  = __shfl(ka, t);
            float po0_t = __shfl(po0, t);
            float po1_t = __shfl(po1, t);
            float pl_t  = __shfl(pl, t);
            float pf_t  = __shfl(pf, t);

            float ss    = __shfl(st, ka_t);
            float num   = po1_t * ss;
            float denom = po0_t * (1.0f - ss) + num;
            float filt  = num * __builtin_amdgcn_rcpf(denom);
            float pred  = pl_t * (1.0f - filt) + (1.0f - pf_t) * filt;
            if (lane == ka_t) st = pred;

            int   kc_t = __shfl(kc, t);
            float cs   = __shfl(st, kc_t);
            float c2   = __shfl(cp2, t);
            float c3   = __shfl(cp3, t);
            float pc   = c2 * (1.0f - cs) + c3 * cs;
            if (lane == t) pc_mine = pc;
        }

        if (lane < T_SZ) probs_out[b * T_SZ + lane] = pc_mine;
        s_state[lane] = st;
    }
    __syncthreads();

    // Expand: state_out[b][j] = s_state[assign[j]]; 4 coalesced float4/thread.
    f32x4* outp = (f32x4*)(state_out + (long)b * N_OBS);
    #pragma unroll
    for (int k = 0; k < 4; ++k) {
        const int i = tid + k * 512;
        const int4 a = pa[k];
        f32x4 v;
        v.x = s_state[a.x];
        v.y = s_state[a.y];
        v.z = s_state[a.z];
        v.w = s_state[a.w];
        __builtin_nontemporal_store(v, &outp[i]);
    }
}

extern "C" void kernel_launch(void* const* d_in, const int* in_sizes, int n_in,
                              void* d_out, int out_size, void* d_ws, size_t ws_size,
                              hipStream_t stream) {
    const int*   prev_kc   = (const int*)  d_in[0];
    const int*   curr_kc   = (const int*)  d_in[1];
    const float* prev_corr = (const float*)d_in[2];
    const float* kc_logits = (const float*)d_in[3];
    const float* A         = (const float*)d_in[4];

    float* probs_out = (float*)d_out;                 // B*T
    float* state_out = (float*)d_out + B_SZ * T_SZ;   // B*N_OBS

    int* assign = (int*)d_ws;                         // 32 KB of workspace

    k_assign<<<(N_OBS * N_KC / 4) / 256, 256, 0, stream>>>(A, assign);
    k_scan_expand<<<B_SZ, 512, 0, stream>>>(prev_kc, curr_kc, prev_corr,
                                            assign, kc_logits,
                                            probs_out, state_out);
}

// Round 7
// 74.495 us; speedup vs baseline: 1.2006x; 1.0063x over previous
//
#include <hip/hip_runtime.h>
#include <hip/hip_bf16.h>
#include <math.h>

#define B_SZ   256
#define T_SZ   50
#define N_OBS  8192
#define N_KC   50

using f32x4 = __attribute__((ext_vector_type(4))) float;

// ---------------------------------------------------------------------------
// K1: assign8[i] = column of the single 1.0 in one-hot row A[i,:], as uint8
//     (N_KC=50 < 256). A is scanned FLAT with float4 (fully coalesced,
//     1.6 MB); each one-hot hit produces one scattered byte store.
// ---------------------------------------------------------------------------
__global__ void __launch_bounds__(256) k_assign(
        const float* __restrict__ A,
        unsigned char* __restrict__ assign8) {
    const int idx = blockIdx.x * 256 + threadIdx.x;   // float4 index
    // N_OBS*N_KC = 409600 floats = 102400 float4 -> exactly 400 blocks.
    const float4 v = ((const float4*)A)[idx];
    const int e = idx * 4;
    if (v.x > 0.5f) assign8[(e + 0) / N_KC] = (unsigned char)((e + 0) % N_KC);
    if (v.y > 0.5f) assign8[(e + 1) / N_KC] = (unsigned char)((e + 1) % N_KC);
    if (v.z > 0.5f) assign8[(e + 2) / N_KC] = (unsigned char)((e + 2) % N_KC);
    if (v.w > 0.5f) assign8[(e + 3) / N_KC] = (unsigned char)((e + 3) % N_KC);
}

// ---------------------------------------------------------------------------
// K2: one 512-thread block per batch element, fused scan + expand.
//     - all 8 waves: sigmoid(kc_logits) -> LDS; prefetch 4 dwords (16 packed
//       uint8 indices) of assign8 (loads complete behind wave 0's scan)
//     - wave 0: per-KC state in registers (lane k < 50), serial recurrence
//       over wave-uniform __shfl broadcasts; v_rcp_f32 on the critical path
//       (threshold 1.1e-2 >> rcp error)
//     - all 8 waves: expand 8192-element row via byte-unpack + LDS gather +
//       nontemporal float4 stores (4 per thread, perfectly coalesced)
// ---------------------------------------------------------------------------
__global__ void __launch_bounds__(512) k_scan_expand(
        const int*   __restrict__ prev_kc,
        const int*   __restrict__ curr_kc,
        const float* __restrict__ prev_corr,
        const unsigned char* __restrict__ assign8,
        const float* __restrict__ kc_logits,
        float* __restrict__ probs_out,    // [B][T]
        float* __restrict__ state_out) {  // [B][N_OBS]
    const int b    = blockIdx.x;
    const int tid  = threadIdx.x;        // 0..511
    const int lane = tid & 63;
    const int wave = tid >> 6;

    __shared__ float s_probs[N_KC * 5 + 6];
    __shared__ float s_state[64];

    for (int i = tid; i < N_KC * 5; i += 512) {
        float x = kc_logits[i];
        s_probs[i] = __builtin_amdgcn_rcpf(1.0f + __expf(-x));
    }

    // Prefetch this thread's expand indices NOW: 4 dwords, each packing 4
    // uint8 assign values; independent of the scan, complete behind it.
    const unsigned int* a32 = (const unsigned int*)assign8;
    unsigned int pa[4];
    #pragma unroll
    for (int k = 0; k < 4; ++k) pa[k] = a32[tid + k * 512];

    __syncthreads();

    if (wave == 0) {
        // Per-step constants: lane t (t < T) holds the values for timestep t.
        int   ka = 0, kc = 0;
        float po0 = 0.f, po1 = 0.f, pl = 0.f, pf = 0.f, cp2 = 0.f, cp3 = 0.f;
        if (lane < T_SZ) {
            int   pk   = prev_kc[b * T_SZ + lane];
            int   ck   = curr_kc[b * T_SZ + lane];
            float corr = prev_corr[b * T_SZ + lane];
            ka = assign8[pk];
            kc = assign8[ck];
            float pp0 = s_probs[ka * 5 + 0];
            float pp1 = s_probs[ka * 5 + 1];
            float pp2 = s_probs[ka * 5 + 2];
            float pp3 = s_probs[ka * 5 + 3];
            // prev_corr is exactly 0.0 or 1.0 -> pow() reduces to a select.
            bool c = corr > 0.5f;
            po0 = c ? pp2 : 1.0f - pp2;
            po1 = c ? pp3 : 1.0f - pp3;
            pl  = pp0;
            pf  = pp1;
            cp2 = s_probs[kc * 5 + 2];
            cp3 = s_probs[kc * 5 + 3];
        }

        // Initial per-KC state: lane k holds sigmoid(kc_logits[k,4]).
        float st = (lane < N_KC) ? s_probs[lane * 5 + 4] : 0.0f;

        float pc_mine = 0.0f;

        // t = 0: prediction only, no state update.
        {
            int   kc0 = __shfl(kc, 0);
            float cs  = __shfl(st, kc0);
            float c2  = __shfl(cp2, 0);
            float c3  = __shfl(cp3, 0);
            float pc  = c2 * (1.0f - cs) + c3 * cs;
            if (lane == 0) pc_mine = pc;
        }

        // t = 1..T-1: serial recurrence; all broadcasts are wave-uniform.
        // The dependent chain is 50 x (shfl, 2 fma, rcp, mul, 2 fma, select)
        // -- the only serial part of the whole problem.
        for (int t = 1; t < T_SZ; ++t) {
            int   ka_t  = __shfl(ka, t);
            float po0_t = __shfl(po0, t);
            float po1_t = __shfl(po1, t);
            float pl_t  = __shfl(pl, t);
            float pf_t  = __shfl(pf, t);

            float ss    = __shfl(st, ka_t);
            float num   = po1_t * ss;
            float denom = po0_t * (1.0f - ss) + num;
            float filt  = num * __builtin_amdgcn_rcpf(denom);
            float pred  = pl_t * (1.0f - filt) + (1.0f - pf_t) * filt;
            if (lane == ka_t) st = pred;

            int   kc_t = __shfl(kc, t);
            float cs   = __shfl(st, kc_t);
            float c2   = __shfl(cp2, t);
            float c3   = __shfl(cp3, t);
            float pc   = c2 * (1.0f - cs) + c3 * cs;
            if (lane == t) pc_mine = pc;
        }

        if (lane < T_SZ) probs_out[b * T_SZ + lane] = pc_mine;
        s_state[lane] = st;
    }
    __syncthreads();

    // Expand: state_out[b][j] = s_state[assign[j]].
    // Unpack 4 uint8 indices per dword, LDS gather, coalesced float4 store.
    f32x4* outp = (f32x4*)(state_out + (long)b * N_OBS);
    #pragma unroll
    for (int k = 0; k < 4; ++k) {
        const int i = tid + k * 512;
        const unsigned int w = pa[k];
        f32x4 v;
        v.x = s_state[w & 0xffu];
        v.y = s_state[(w >> 8)  & 0xffu];
        v.z = s_state[(w >> 16) & 0xffu];
        v.w = s_state[(w >> 24) & 0xffu];
        __builtin_nontemporal_store(v, &outp[i]);
    }
}

extern "C" void kernel_launch(void* const* d_in, const int* in_sizes, int n_in,
                              void* d_out, int out_size, void* d_ws, size_t ws_size,
                              hipStream_t stream) {
    const int*   prev_kc   = (const int*)  d_in[0];
    const int*   curr_kc   = (const int*)  d_in[1];
    const float* prev_corr = (const float*)d_in[2];
    const float* kc_logits = (const float*)d_in[3];
    const float* A         = (const float*)d_in[4];

    float* probs_out = (float*)d_out;                 // B*T
    float* state_out = (float*)d_out + B_SZ * T_SZ;   // B*N_OBS

    unsigned char* assign8 = (unsigned char*)d_ws;    // 8 KB of workspace

    k_assign<<<(N_OBS * N_KC / 4) / 256, 256, 0, stream>>>(A, assign8);
    k_scan_expand<<<B_SZ, 512, 0, stream>>>(prev_kc, curr_kc, prev_corr,
                                            assign8, kc_logits,
                                            probs_out, state_out);
}